// Round 10
// baseline (50.790 us; speedup 1.0000x reference)
//
#include <hip/hip_runtime.h>
#include <hip/hip_bf16.h>

#define IN_C 192
#define HW   9600     // 80*120
#define NPIX 128      // pixels per tile (8 waves x 16-px strips)
#define NT_PER_B 75   // tiles per batch image
#define NTILES 1200
#define NBLK 512      // single dispatch round: 2 blocks/CU x 256 CU

typedef __attribute__((ext_vector_type(8))) short bf16x8;
typedef __attribute__((ext_vector_type(4))) float f32x4;

static __device__ __forceinline__ short f2bf(float f) {
  return __builtin_bit_cast(short, __float2bfloat16(f));   // RNE
}

// Pack W (192x192 fp32, row-major [o][k]) into fragment-sequential bf16:
// frag (fo, kk): 64 lanes x 8 bf16 (16B/lane), lane l -> o = fo*16 + (l&15),
// k = kk*32 + (l>>4)*8 + j. Same k(l,j) convention as the x B-frags, so any
// true intra-fragment k-permutation of the HW layout cancels (validated R1).
__global__ void pack_w_kernel(const float* __restrict__ W, short* __restrict__ wp) {
  int idx = blockIdx.x * 256 + threadIdx.x;   // 0 .. 4607
  if (idx >= 12 * 6 * 64) return;
  int fo  = idx / (6 * 64);
  int rem = idx % (6 * 64);
  int kk  = rem / 64;
  int l   = rem % 64;
  int o   = fo * 16 + (l & 15);
  int kb  = kk * 32 + (l >> 4) * 8;
  bf16x8 v;
#pragma unroll
  for (int j = 0; j < 8; ++j) v[j] = f2bf(W[o * IN_C + kb + j]);
  *reinterpret_cast<bf16x8*>(wp + (size_t)idx * 8) = v;
}

// Single-round persistent kernel: 512 blocks, bid<176 run 3 tiles, else 2
// (exactly 1200, no dummy work - R8's +17MB fetch and +28% compute removed).
// Straight-line bodies (R7 scratch-spill lesson); 4-buffer x rotation threads
// statically across bodies so the vmcnt FIFO never drains mid-block.
// Invariants (R5/R6 validated): W is staged once to LDS via global_load_lds
// (af reads are lgkmcnt) so the K-steps' ONLY vmcnt ops are x prefetches;
// no barriers after the prologue; x read exactly once; bias in LDS.
__global__ __launch_bounds__(512, 4) void conv_mfma_kernel(
    const float* __restrict__ x, const short* __restrict__ wp,
    const float* __restrict__ bias, float* __restrict__ out) {
  __shared__ short wl[12 * 6 * 64 * 8];   // 73728 B packed-fragment W
  __shared__ __align__(16) float bl[192];

  const int tid  = threadIdx.x;
  const int wid  = tid >> 6;
  const int lane = tid & 63;
  const int c    = lane & 15;
  const int g    = lane >> 4;
  const int bid  = blockIdx.x;

  const int  t0    = bid;
  const int  t1    = bid + NBLK;
  const bool third = (bid < NTILES - 2 * NBLK);   // 176 blocks get a 3rd tile
  const int  t2    = bid + 2 * NBLK;

#define XPTR(T)                                                       \
  (x + (size_t)((T) / NT_PER_B) * (IN_C * HW)                         \
     + ((T) % NT_PER_B) * NPIX + (size_t)(g * 8) * HW + wid * 16 + c)

#define LOADX(DST, PTR, KK)                                           \
  { _Pragma("unroll")                                                 \
    for (int j = 0; j < 8; ++j)                                       \
      DST[j] = (PTR)[(size_t)((KK) * 32 + j) * HW]; }

  const float* xp0 = XPTR(t0);
  const float* xp1 = XPTR(t1);
  const float* xp2 = XPTR(t2);

  float xA[8], xB[8], xC[8], xD[8];

  // ---- Prologue: x k0..k2 first (long HBM latency), then W -> LDS ----
  LOADX(xA, xp0, 0);
  LOADX(xB, xp0, 1);
  LOADX(xC, xp0, 2);
#pragma unroll
  for (int i = 0; i < 9; ++i) {
    const int chunk = i * 512 + tid;     // 0..4607
    const short* src = wp + (size_t)chunk * 8;
    short* dst = wl + (size_t)chunk * 8;
    __builtin_amdgcn_global_load_lds(
        (const __attribute__((address_space(1))) void*)src,
        (__attribute__((address_space(3))) void*)dst, 16, 0, 0);
  }
  if (tid < 192) bl[tid] = bias[tid];
  __syncthreads();   // W+bias staged; everything below is barrier-free

  // KSTEP: optional prefetch, then consume CURB at k-step KK.
  // af from LDS in batches of 3 (12 transient VGPRs).
#define KSTEP(CURB, PFB, PFPTR, PFKK, PFEN, KK)                       \
  {                                                                   \
    if (PFEN) { LOADX(PFB, PFPTR, PFKK); }                            \
    bf16x8 bfr;                                                       \
    _Pragma("unroll")                                                 \
    for (int j = 0; j < 8; ++j) bfr[j] = f2bf(CURB[j]);               \
    _Pragma("unroll")                                                 \
    for (int h = 0; h < 4; ++h) {                                     \
      bf16x8 af[3];                                                   \
      _Pragma("unroll")                                               \
      for (int m = 0; m < 3; ++m)                                     \
        af[m] = *reinterpret_cast<const bf16x8*>(                     \
            wl + (size_t)((((h * 3 + m) * 6 + (KK)) * 64) + lane) * 8); \
      _Pragma("unroll")                                               \
      for (int m = 0; m < 3; ++m)                                     \
        acc[h * 3 + m] = __builtin_amdgcn_mfma_f32_16x16x32_bf16(     \
            af[m], bfr, acc[h * 3 + m], 0, 0, 0);                     \
    }                                                                 \
  }

  // BODY: consume order NW,NX,NY,NZ,NW,NX (4-buf rotation); steps 0-2
  // prefetch own k3..k5, steps 3-5 prefetch NXTP's k0..k2 (enables E6..E8).
#define BODY(T, CURP, NXTP, E6, E7, E8, NW, NX, NY, NZ)               \
  {                                                                   \
    f32x4 acc[12];                                                    \
    _Pragma("unroll")                                                 \
    for (int m = 0; m < 12; ++m) acc[m] = (f32x4)0.0f;                \
    KSTEP(NW, NZ, CURP, 3, true, 0);                                  \
    KSTEP(NX, NW, CURP, 4, true, 1);                                  \
    KSTEP(NY, NX, CURP, 5, true, 2);                                  \
    KSTEP(NZ, NY, NXTP, 0, E6,   3);                                  \
    KSTEP(NW, NZ, NXTP, 1, E7,   4);                                  \
    KSTEP(NX, NW, NXTP, 2, E8,   5);                                  \
    const int tb = (T) / NT_PER_B;                                    \
    const int p  = ((T) % NT_PER_B) * NPIX + wid * 16 + c;            \
    const int hi = p / 120;                                           \
    const int wi = p - hi * 120;                                      \
    _Pragma("unroll")                                                 \
    for (int mo = 0; mo < 12; ++mo) {                                 \
      const int ob = mo * 16 + g * 4;                                 \
      const f32x4 bv = *reinterpret_cast<const f32x4*>(bl + ob);      \
      const f32x4 v  = acc[mo];                                       \
      _Pragma("unroll")                                               \
      for (int r = 0; r < 4; ++r) {                                   \
        const int o  = ob + r;                                        \
        const int co = o >> 6;                                        \
        const int br = (o >> 3) & 7;                                  \
        const int bc = o & 7;                                         \
        const int idx = ((tb * 3 + co) * 640 + br * 80 + hi) * 960    \
                        + bc * 120 + wi;                              \
        out[idx] = v[r] + bv[r];                                      \
      }                                                               \
    }                                                                 \
  }

  // body0: consumes k0..k5 (A,B,C,D,A,B), prefetches t1's k0..k2 into C,D,A
  BODY(t0, xp0, xp1, true, true, true, xA, xB, xC, xD);
  // body1: consumes k6..k11 (C,D,A,B,C,D), prefetches t2's k0..k2 iff third
  BODY(t1, xp1, xp2, third, third, third, xC, xD, xA, xB);
  // body2 (uniform branch): consumes k12..k17 (A,B,C,D,A,B), no next
  if (third) {
    BODY(t2, xp2, xp2, false, false, false, xA, xB, xC, xD);
  }

#undef BODY
#undef KSTEP
#undef LOADX
#undef XPTR
}

extern "C" void kernel_launch(void* const* d_in, const int* in_sizes, int n_in,
                              void* d_out, int out_size, void* d_ws, size_t ws_size,
                              hipStream_t stream) {
  const float* x    = (const float*)d_in[0];
  const float* W    = (const float*)d_in[1];
  const float* bias = (const float*)d_in[2];
  float* out = (float*)d_out;
  short* wp  = (short*)d_ws;   // 192*192 bf16 packed-fragment W (73728 B)

  pack_w_kernel<<<18, 256, 0, stream>>>(W, wp);
  conv_mfma_kernel<<<NBLK, 512, 0, stream>>>(x, wp, bias, out);
}